// Round 1
// baseline (1040.462 us; speedup 1.0000x reference)
//
#include <hip/hip_runtime.h>
#include <math.h>

// Problem constants
#define KP   10      // prototypes per side
#define CC   768     // channels
#define NB   8       // batch
#define HW   4096    // 64*64
#define STOT 32768   // NB*HW
#define NS   12      // N_SAMPLES

// Workspace layout (float offsets)
#define WS_SCORE_FG 0
#define WS_SCORE_BG 32768
#define WS_SEL      65536   // 24 ints
#define WS_FEATS    65600   // 24*768 floats (pos 12 rows, then neg 12 rows)
#define WS_PFG      84032   // 10*768
#define WS_PBG      91712   // 10*768

// ---------------- K1: per-pixel norm + max-sim scores ----------------
__global__ __launch_bounds__(64) void k_scores(const float* __restrict__ fg,
                                               const float* __restrict__ bg,
                                               const float* __restrict__ F,
                                               const float* __restrict__ M,
                                               float* __restrict__ sfg,
                                               float* __restrict__ sbg) {
    int s = blockIdx.x * 64 + threadIdx.x;
    int n = s >> 12, hw = s & 4095;
    const float* fp = F + ((size_t)n * CC) * HW + hw;

    float afg[KP], abg[KP], norm2 = 0.f;
#pragma unroll
    for (int k = 0; k < KP; ++k) { afg[k] = 0.f; abg[k] = 0.f; }

    for (int c0 = 0; c0 < CC; c0 += 16) {
        float f[16];
#pragma unroll
        for (int j = 0; j < 16; ++j) f[j] = fp[(size_t)(c0 + j) * HW];
#pragma unroll
        for (int j = 0; j < 16; ++j) {
            float fv = f[j];
            norm2 = fmaf(fv, fv, norm2);
#pragma unroll
            for (int k = 0; k < KP; ++k) afg[k] = fmaf(fv, fg[k * CC + c0 + j], afg[k]);
#pragma unroll
            for (int k = 0; k < KP; ++k) abg[k] = fmaf(fv, bg[k * CC + c0 + j], abg[k]);
        }
    }
    float mfg = afg[0], mbg = abg[0];
#pragma unroll
    for (int k = 1; k < KP; ++k) { mfg = fmaxf(mfg, afg[k]); mbg = fmaxf(mbg, abg[k]); }
    float nc = fmaxf(sqrtf(norm2), 1e-8f);
    float m  = fminf(fmaxf(M[s], 0.f), 1.f);
    sfg[s] = (1.f - mfg / nc) * m;
    sbg[s] = (1.f - mbg / nc) * (1.f - m);
}

// ---------------- K2: exact top-12 (value desc, index asc) ----------------
__global__ __launch_bounds__(256) void k_topk(const float* __restrict__ ws, int* __restrict__ sel) {
    const float* sc = ws + (blockIdx.x == 0 ? WS_SCORE_FG : WS_SCORE_BG);
    int* out = sel + blockIdx.x * NS;
    __shared__ float bv[256];
    __shared__ int   bi[256];
    __shared__ int   chosen[NS];
    int tid = threadIdx.x;

    for (int r = 0; r < NS; ++r) {
        float best = -1e30f; int bidx = 1 << 30;
        for (int i = tid; i < STOT; i += 256) {
            float v = sc[i];
            bool skip = false;
            for (int j = 0; j < r; ++j) if (chosen[j] == i) skip = true;
            if (!skip && v > best) { best = v; bidx = i; }   // strict > keeps lowest index within thread
        }
        bv[tid] = best; bi[tid] = bidx;
        __syncthreads();
        for (int off = 128; off > 0; off >>= 1) {
            if (tid < off) {
                float v2 = bv[tid + off]; int i2 = bi[tid + off];
                if (v2 > bv[tid] || (v2 == bv[tid] && i2 < bi[tid])) { bv[tid] = v2; bi[tid] = i2; }
            }
            __syncthreads();
        }
        if (tid == 0) { chosen[r] = bi[0]; out[r] = bi[0]; }
        __syncthreads();
    }
}

// ---------------- K3: gather selected pixels + normalize ----------------
__global__ __launch_bounds__(256) void k_gather(const float* __restrict__ F,
                                                const int* __restrict__ sel,
                                                float* __restrict__ feats) {
    int b = blockIdx.x;                  // 0..23
    int s = sel[b];
    int n = s >> 12, hw = s & 4095;
    const float* fp = F + ((size_t)n * CC) * HW + hw;
    int tid = threadIdx.x;

    float v0 = fp[(size_t)(tid)       * HW];
    float v1 = fp[(size_t)(tid + 256) * HW];
    float v2 = fp[(size_t)(tid + 512) * HW];
    __shared__ float red[256];
    red[tid] = v0 * v0 + v1 * v1 + v2 * v2;
    __syncthreads();
    for (int off = 128; off > 0; off >>= 1) { if (tid < off) red[tid] += red[tid + off]; __syncthreads(); }
    float inv = 1.f / fmaxf(sqrtf(red[0]), 1e-8f);
    feats[b * CC + tid]       = v0 * inv;
    feats[b * CC + tid + 256] = v1 * inv;
    feats[b * CC + tid + 512] = v2 * inv;
}

// ---------------- K4: iterative refinement (block 0: fg, block 1: bg) ----------------
__global__ __launch_bounds__(256) void k_refine(const float* __restrict__ feats_all,
                                                const float* __restrict__ fg,
                                                const float* __restrict__ bg,
                                                float* __restrict__ pfg,
                                                float* __restrict__ pbg) {
    __shared__ float fe[NS * CC];
    __shared__ float pp[KP * CC];
    __shared__ float tmp[KP * CC];
    __shared__ float dots[NS * KP];
    __shared__ int   assign[NS];
    __shared__ float cntf[KP];
    __shared__ float red[256 * KP];
    __shared__ float nrm[KP];

    const int tid = threadIdx.x;
    const float* feats = feats_all + blockIdx.x * (NS * CC);
    const float* p0    = (blockIdx.x == 0) ? fg : bg;
    float* pout        = (blockIdx.x == 0) ? pfg : pbg;

    for (int i = tid; i < NS * CC; i += 256) fe[i] = feats[i];
    for (int i = tid; i < KP * CC; i += 256) pp[i] = p0[i];
    __syncthreads();

    const int wave = tid >> 6, lane = tid & 63;

    for (int it = 0; it < 10; ++it) {
        float step = 0.1f / (1.0f + 0.5f * (float)it);

        // dots[s][k] = <fe_s, pp_k> ; one wave per (s,k) pair
        for (int pid = wave; pid < NS * KP; pid += 4) {
            int s = pid / KP, k = pid % KP;
            const float4* fr = (const float4*)&fe[s * CC + lane * 12];
            const float4* pr = (const float4*)&pp[k * CC + lane * 12];
            float acc = 0.f;
#pragma unroll
            for (int j = 0; j < 3; ++j) {
                float4 a = fr[j], b = pr[j];
                acc += a.x * b.x + a.y * b.y + a.z * b.z + a.w * b.w;
            }
#pragma unroll
            for (int m2 = 1; m2 < 64; m2 <<= 1) acc += __shfl_xor(acc, m2, 64);
            if (lane == 0) dots[s * KP + k] = acc;
        }
        __syncthreads();

        if (tid < NS) {
            int best = 0; float bvv = dots[tid * KP];
#pragma unroll
            for (int k = 1; k < KP; ++k) { float v = dots[tid * KP + k]; if (v > bvv) { bvv = v; best = k; } }
            assign[tid] = best;
        }
        __syncthreads();
        if (tid < KP) {
            int c = 0;
            for (int s = 0; s < NS; ++s) c += (assign[s] == tid);
            cntf[tid] = (float)c;
        }
        __syncthreads();

        // blend + accumulate row sums of squares
        float ss[KP];
#pragma unroll
        for (int k = 0; k < KP; ++k) ss[k] = 0.f;
        for (int cc = 0; cc < 3; ++cc) {
            int c = tid + cc * 256;
            float acc[KP];
#pragma unroll
            for (int k = 0; k < KP; ++k) acc[k] = 0.f;
            for (int s = 0; s < NS; ++s) {
                int a = assign[s];
                float v = fe[s * CC + c];
#pragma unroll
                for (int k = 0; k < KP; ++k) acc[k] += (a == k) ? v : 0.f;
            }
#pragma unroll
            for (int k = 0; k < KP; ++k) {
                float mean = acc[k] / fmaxf(cntf[k], 1.0f);
                float v = (1.0f - step) * pp[k * CC + c] + step * mean;
                tmp[k * CC + c] = v;
                ss[k] += v * v;
            }
        }
#pragma unroll
        for (int k = 0; k < KP; ++k) red[tid * KP + k] = ss[k];
        __syncthreads();
        for (int off = 128; off > 0; off >>= 1) {
            if (tid < off) {
#pragma unroll
                for (int k = 0; k < KP; ++k) red[tid * KP + k] += red[(tid + off) * KP + k];
            }
            __syncthreads();
        }
        if (tid < KP) nrm[tid] = sqrtf(red[tid]);
        __syncthreads();
        for (int cc = 0; cc < 3; ++cc) {
            int c = tid + cc * 256;
#pragma unroll
            for (int k = 0; k < KP; ++k) {
                if (cntf[k] > 0.f) pp[k * CC + c] = tmp[k * CC + c] / fmaxf(nrm[k], 1e-8f);
            }
        }
        __syncthreads();
    }
    for (int i = tid; i < KP * CC; i += 256) pout[i] = pp[i];
}

// ---------------- K5: triplet + InfoNCE loss ----------------
__global__ __launch_bounds__(256) void k_loss(const float* __restrict__ feats,
                                              const float* __restrict__ pfg,
                                              const float* __restrict__ pbg,
                                              float* __restrict__ out) {
    __shared__ float dots3[NS * 30];   // [s][g*10+k]: g=0 pos@pfg, g=1 neg@pfg, g=2 pos@pbg
    __shared__ float mp[NS], mn[NS], infon[NS];
    int tid = threadIdx.x, wave = tid >> 6, lane = tid & 63;

    for (int pid = wave; pid < 360; pid += 4) {
        int g = pid / 120, r = pid % 120, s = r / KP, k = r % KP;
        const float4* a4 = (const float4*)(feats + ((g == 1 ? NS + s : s) * CC) + lane * 12);
        const float4* b4 = (const float4*)((g == 2 ? pbg : pfg) + k * CC + lane * 12);
        float acc = 0.f;
#pragma unroll
        for (int j = 0; j < 3; ++j) {
            float4 a = a4[j], b = b4[j];
            acc += a.x * b.x + a.y * b.y + a.z * b.z + a.w * b.w;
        }
#pragma unroll
        for (int m2 = 1; m2 < 64; m2 <<= 1) acc += __shfl_xor(acc, m2, 64);
        if (lane == 0) dots3[s * 30 + g * 10 + k] = acc;
    }
    __syncthreads();

    if (tid < NS) {
        const float* d = &dots3[tid * 30];
        float maxp = d[0], maxn = d[10];
#pragma unroll
        for (int k = 1; k < KP; ++k) { maxp = fmaxf(maxp, d[k]); maxn = fmaxf(maxn, d[10 + k]); }
        mp[tid] = maxp; mn[tid] = maxn;

        float x[KP], y[KP];
#pragma unroll
        for (int k = 0; k < KP; ++k) { x[k] = d[k] / 0.07f; y[k] = d[20 + k] / 0.07f; }
        float m10 = x[0];
#pragma unroll
        for (int k = 1; k < KP; ++k) m10 = fmaxf(m10, x[k]);
        float se = 0.f;
#pragma unroll
        for (int k = 0; k < KP; ++k) se += expf(x[k] - m10);
        float numer = logf(se) + m10;
        float m20 = m10;
#pragma unroll
        for (int k = 0; k < KP; ++k) m20 = fmaxf(m20, y[k]);
        float se2 = 0.f;
#pragma unroll
        for (int k = 0; k < KP; ++k) se2 += expf(x[k] - m20);
#pragma unroll
        for (int k = 0; k < KP; ++k) se2 += expf(y[k] - m20);
        float denom = logf(se2) + m20;
        infon[tid] = numer - denom;
    }
    __syncthreads();
    if (tid == 0) {
        float sp = 0.f, sn = 0.f, si = 0.f;
        for (int s = 0; s < NS; ++s) { sp += mp[s]; sn += mn[s]; si += infon[s]; }
        sp /= 12.f; sn /= 12.f; si /= 12.f;
        float loss = fmaxf(0.2f + sn - sp, 0.f) + 0.25f * (-si);
        out[0] = loss;
    }
}

// ---------------- K6: blend + renormalize refined prototypes ----------------
__global__ __launch_bounds__(256) void k_blend(const float* __restrict__ fg,
                                               const float* __restrict__ bg,
                                               const float* __restrict__ pfg,
                                               const float* __restrict__ pbg,
                                               float* __restrict__ out) {
    __shared__ float red[256];
    int r = blockIdx.x, tid = threadIdx.x;
    const float* a = (r < 10) ? (fg + r * CC) : (bg + (r - 10) * CC);
    const float* b = (r < 10) ? (pfg + r * CC) : (pbg + (r - 10) * CC);
    float v[3]; float ss = 0.f;
#pragma unroll
    for (int cc = 0; cc < 3; ++cc) {
        int c = tid + cc * 256;
        v[cc] = (1.0f - 0.3f) * a[c] + 0.3f * b[c];
        ss += v[cc] * v[cc];
    }
    red[tid] = ss; __syncthreads();
    for (int off = 128; off > 0; off >>= 1) { if (tid < off) red[tid] += red[tid + off]; __syncthreads(); }
    float inv = 1.f / fmaxf(sqrtf(red[0]), 1e-8f);
    float* o = out + 1 + r * CC;   // fg rows 0..9, bg rows 10..19 are contiguous in out
#pragma unroll
    for (int cc = 0; cc < 3; ++cc) o[tid + cc * 256] = v[cc] * inv;
}

extern "C" void kernel_launch(void* const* d_in, const int* in_sizes, int n_in,
                              void* d_out, int out_size, void* d_ws, size_t ws_size,
                              hipStream_t stream) {
    const float* fg = (const float*)d_in[0];   // [10,768]
    const float* bg = (const float*)d_in[1];   // [10,768]
    const float* F  = (const float*)d_in[2];   // [8,768,64,64]
    const float* M  = (const float*)d_in[3];   // [8,1,64,64]
    float* out = (float*)d_out;                // [1 + 7680 + 7680]

    float* w   = (float*)d_ws;
    float* sfg = w + WS_SCORE_FG;
    float* sbg = w + WS_SCORE_BG;
    int*   sel = (int*)(w + WS_SEL);
    float* fea = w + WS_FEATS;
    float* pfg = w + WS_PFG;
    float* pbg = w + WS_PBG;

    k_scores<<<STOT / 64, 64, 0, stream>>>(fg, bg, F, M, sfg, sbg);
    k_topk  <<<2, 256, 0, stream>>>(w, sel);
    k_gather<<<24, 256, 0, stream>>>(F, sel, fea);
    k_refine<<<2, 256, 0, stream>>>(fea, fg, bg, pfg, pbg);
    k_loss  <<<1, 256, 0, stream>>>(fea, pfg, pbg, out);
    k_blend <<<20, 256, 0, stream>>>(fg, bg, pfg, pbg, out);
}

// Round 2
// 530.744 us; speedup vs baseline: 1.9604x; 1.9604x over previous
//
#include <hip/hip_runtime.h>
#include <math.h>

// Problem constants
#define KP   10      // prototypes per side
#define CC   768     // channels
#define NB   8       // batch
#define HW   4096    // 64*64
#define STOT 32768   // NB*HW
#define NS   12      // N_SAMPLES

// Workspace layout (float offsets)
#define WS_SCORE_FG 0
#define WS_SCORE_BG 32768
#define WS_SEL      65536   // 24 ints
#define WS_FEATS    65600   // 24*768 floats (pos 12 rows, then neg 12 rows)
#define WS_PFG      84032   // 10*768
#define WS_PBG      91712   // 10*768

// ---------------- K1: per-pixel norm + max-sim scores ----------------
__global__ __launch_bounds__(64) void k_scores(const float* __restrict__ fg,
                                               const float* __restrict__ bg,
                                               const float* __restrict__ F,
                                               const float* __restrict__ M,
                                               float* __restrict__ sfg,
                                               float* __restrict__ sbg) {
    int s = blockIdx.x * 64 + threadIdx.x;
    int n = s >> 12, hw = s & 4095;
    const float* fp = F + ((size_t)n * CC) * HW + hw;

    float afg[KP], abg[KP], norm2 = 0.f;
#pragma unroll
    for (int k = 0; k < KP; ++k) { afg[k] = 0.f; abg[k] = 0.f; }

    for (int c0 = 0; c0 < CC; c0 += 16) {
        float f[16];
#pragma unroll
        for (int j = 0; j < 16; ++j) f[j] = fp[(size_t)(c0 + j) * HW];
#pragma unroll
        for (int j = 0; j < 16; ++j) {
            float fv = f[j];
            norm2 = fmaf(fv, fv, norm2);
#pragma unroll
            for (int k = 0; k < KP; ++k) afg[k] = fmaf(fv, fg[k * CC + c0 + j], afg[k]);
#pragma unroll
            for (int k = 0; k < KP; ++k) abg[k] = fmaf(fv, bg[k * CC + c0 + j], abg[k]);
        }
    }
    float mfg = afg[0], mbg = abg[0];
#pragma unroll
    for (int k = 1; k < KP; ++k) { mfg = fmaxf(mfg, afg[k]); mbg = fmaxf(mbg, abg[k]); }
    float nc = fmaxf(sqrtf(norm2), 1e-8f);
    float m  = fminf(fmaxf(M[s], 0.f), 1.f);
    sfg[s] = (1.f - mfg / nc) * m;
    sbg[s] = (1.f - mbg / nc) * (1.f - m);
}

// ---------------- K2: exact top-12, single pass ----------------
// Per-thread sorted top-12 in registers (static-index unrolled insertion),
// then LDS candidate-pool merge with (value desc, index asc) tie-break.
__global__ __launch_bounds__(256) void k_topk(const float* __restrict__ ws, int* __restrict__ sel) {
    const float* sc = ws + (blockIdx.x == 0 ? WS_SCORE_FG : WS_SCORE_BG);
    int* out = sel + blockIdx.x * NS;
    const int tid = threadIdx.x;
    const int wave = tid >> 6, lane = tid & 63;

    float tv[NS]; int ti[NS];
#pragma unroll
    for (int j = 0; j < NS; ++j) { tv[j] = -1e30f; ti[j] = 0x3fffffff; }

    // Single pass: float4 loads; indices ascend within a thread, so strict-'>'
    // insertion keeps the lowest index on equal values (lax.top_k semantics).
    const float4* sc4 = (const float4*)sc;
    for (int r = 0; r < STOT / 4 / 256; ++r) {   // 32 iterations
        int i4 = r * 256 + tid;
        float4 v4 = sc4[i4];
        float vs[4] = {v4.x, v4.y, v4.z, v4.w};
#pragma unroll
        for (int j = 0; j < 4; ++j) {
            float v = vs[j];
            int idx = i4 * 4 + j;
            if (v > tv[NS - 1]) {
#pragma unroll
                for (int q = NS - 1; q >= 1; --q) {
                    bool shift = v > tv[q - 1];            // insert pos < q: shift down
                    bool here  = !shift && (v > tv[q]);    // insert exactly at q
                    float ntv = shift ? tv[q - 1] : (here ? v : tv[q]);
                    int   nti = shift ? ti[q - 1] : (here ? idx : ti[q]);
                    tv[q] = ntv; ti[q] = nti;
                }
                if (v > tv[0]) { tv[0] = v; ti[0] = idx; }
            }
        }
    }

    // Candidate pool in LDS (stride 13 to avoid 8-way bank conflicts)
    __shared__ float pv[256 * 13];
    __shared__ int   pi[256 * 13];
    __shared__ float rv[4];
    __shared__ int   ri[4];
    __shared__ int   besti_sh;
#pragma unroll
    for (int j = 0; j < NS; ++j) { pv[tid * 13 + j] = tv[j]; pi[tid * 13 + j] = ti[j]; }
    __syncthreads();

    for (int r = 0; r < NS; ++r) {
        // local best over own 12 entries
        float bv = -1e30f; int bi2 = 0x7fffffff;
#pragma unroll
        for (int j = 0; j < NS; ++j) {
            float v = pv[tid * 13 + j]; int idx = pi[tid * 13 + j];
            if (v > bv || (v == bv && idx < bi2)) { bv = v; bi2 = idx; }
        }
        // wave reduce with tie-break
#pragma unroll
        for (int m2 = 1; m2 < 64; m2 <<= 1) {
            float ov = __shfl_xor(bv, m2, 64);
            int   oi = __shfl_xor(bi2, m2, 64);
            if (ov > bv || (ov == bv && oi < bi2)) { bv = ov; bi2 = oi; }
        }
        if (lane == 0) { rv[wave] = bv; ri[wave] = bi2; }
        __syncthreads();
        if (tid == 0) {
            float fb = rv[0]; int fi = ri[0];
#pragma unroll
            for (int w2 = 1; w2 < 4; ++w2) {
                if (rv[w2] > fb || (rv[w2] == fb && ri[w2] < fi)) { fb = rv[w2]; fi = ri[w2]; }
            }
            out[r] = fi;
            besti_sh = fi;
        }
        __syncthreads();
        int fi = besti_sh;
        // each pixel index lives in exactly one thread's pool -> clear own copy
#pragma unroll
        for (int j = 0; j < NS; ++j) {
            if (pi[tid * 13 + j] == fi) pv[tid * 13 + j] = -1e30f;
        }
        __syncthreads();
    }
}

// ---------------- K3: gather selected pixels + normalize ----------------
__global__ __launch_bounds__(256) void k_gather(const float* __restrict__ F,
                                                const int* __restrict__ sel,
                                                float* __restrict__ feats) {
    int b = blockIdx.x;                  // 0..23
    int s = sel[b];
    int n = s >> 12, hw = s & 4095;
    const float* fp = F + ((size_t)n * CC) * HW + hw;
    int tid = threadIdx.x;

    float v0 = fp[(size_t)(tid)       * HW];
    float v1 = fp[(size_t)(tid + 256) * HW];
    float v2 = fp[(size_t)(tid + 512) * HW];
    __shared__ float red[256];
    red[tid] = v0 * v0 + v1 * v1 + v2 * v2;
    __syncthreads();
    for (int off = 128; off > 0; off >>= 1) { if (tid < off) red[tid] += red[tid + off]; __syncthreads(); }
    float inv = 1.f / fmaxf(sqrtf(red[0]), 1e-8f);
    feats[b * CC + tid]       = v0 * inv;
    feats[b * CC + tid + 256] = v1 * inv;
    feats[b * CC + tid + 512] = v2 * inv;
}

// ---------------- K4: iterative refinement (block 0: fg, block 1: bg) ----------------
__global__ __launch_bounds__(256) void k_refine(const float* __restrict__ feats_all,
                                                const float* __restrict__ fg,
                                                const float* __restrict__ bg,
                                                float* __restrict__ pfg,
                                                float* __restrict__ pbg) {
    __shared__ float fe[NS * CC];
    __shared__ float pp[KP * CC];
    __shared__ float tmp[KP * CC];
    __shared__ float dots[NS * KP];
    __shared__ int   assign[NS];
    __shared__ float cntf[KP];
    __shared__ float red[256 * KP];
    __shared__ float nrm[KP];

    const int tid = threadIdx.x;
    const float* feats = feats_all + blockIdx.x * (NS * CC);
    const float* p0    = (blockIdx.x == 0) ? fg : bg;
    float* pout        = (blockIdx.x == 0) ? pfg : pbg;

    for (int i = tid; i < NS * CC; i += 256) fe[i] = feats[i];
    for (int i = tid; i < KP * CC; i += 256) pp[i] = p0[i];
    __syncthreads();

    const int wave = tid >> 6, lane = tid & 63;

    for (int it = 0; it < 10; ++it) {
        float step = 0.1f / (1.0f + 0.5f * (float)it);

        // dots[s][k] = <fe_s, pp_k> ; one wave per (s,k) pair
        for (int pid = wave; pid < NS * KP; pid += 4) {
            int s = pid / KP, k = pid % KP;
            const float4* fr = (const float4*)&fe[s * CC + lane * 12];
            const float4* pr = (const float4*)&pp[k * CC + lane * 12];
            float acc = 0.f;
#pragma unroll
            for (int j = 0; j < 3; ++j) {
                float4 a = fr[j], b = pr[j];
                acc += a.x * b.x + a.y * b.y + a.z * b.z + a.w * b.w;
            }
#pragma unroll
            for (int m2 = 1; m2 < 64; m2 <<= 1) acc += __shfl_xor(acc, m2, 64);
            if (lane == 0) dots[s * KP + k] = acc;
        }
        __syncthreads();

        if (tid < NS) {
            int best = 0; float bvv = dots[tid * KP];
#pragma unroll
            for (int k = 1; k < KP; ++k) { float v = dots[tid * KP + k]; if (v > bvv) { bvv = v; best = k; } }
            assign[tid] = best;
        }
        __syncthreads();
        if (tid < KP) {
            int c = 0;
            for (int s = 0; s < NS; ++s) c += (assign[s] == tid);
            cntf[tid] = (float)c;
        }
        __syncthreads();

        // blend + accumulate row sums of squares
        float ss[KP];
#pragma unroll
        for (int k = 0; k < KP; ++k) ss[k] = 0.f;
        for (int cc = 0; cc < 3; ++cc) {
            int c = tid + cc * 256;
            float acc[KP];
#pragma unroll
            for (int k = 0; k < KP; ++k) acc[k] = 0.f;
            for (int s = 0; s < NS; ++s) {
                int a = assign[s];
                float v = fe[s * CC + c];
#pragma unroll
                for (int k = 0; k < KP; ++k) acc[k] += (a == k) ? v : 0.f;
            }
#pragma unroll
            for (int k = 0; k < KP; ++k) {
                float mean = acc[k] / fmaxf(cntf[k], 1.0f);
                float v = (1.0f - step) * pp[k * CC + c] + step * mean;
                tmp[k * CC + c] = v;
                ss[k] += v * v;
            }
        }
#pragma unroll
        for (int k = 0; k < KP; ++k) red[tid * KP + k] = ss[k];
        __syncthreads();
        for (int off = 128; off > 0; off >>= 1) {
            if (tid < off) {
#pragma unroll
                for (int k = 0; k < KP; ++k) red[tid * KP + k] += red[(tid + off) * KP + k];
            }
            __syncthreads();
        }
        if (tid < KP) nrm[tid] = sqrtf(red[tid]);
        __syncthreads();
        for (int cc = 0; cc < 3; ++cc) {
            int c = tid + cc * 256;
#pragma unroll
            for (int k = 0; k < KP; ++k) {
                if (cntf[k] > 0.f) pp[k * CC + c] = tmp[k * CC + c] / fmaxf(nrm[k], 1e-8f);
            }
        }
        __syncthreads();
    }
    for (int i = tid; i < KP * CC; i += 256) pout[i] = pp[i];
}

// ---------------- K5: triplet + InfoNCE loss ----------------
__global__ __launch_bounds__(256) void k_loss(const float* __restrict__ feats,
                                              const float* __restrict__ pfg,
                                              const float* __restrict__ pbg,
                                              float* __restrict__ out) {
    __shared__ float dots3[NS * 30];   // [s][g*10+k]: g=0 pos@pfg, g=1 neg@pfg, g=2 pos@pbg
    __shared__ float mp[NS], mn[NS], infon[NS];
    int tid = threadIdx.x, wave = tid >> 6, lane = tid & 63;

    for (int pid = wave; pid < 360; pid += 4) {
        int g = pid / 120, r = pid % 120, s = r / KP, k = r % KP;
        const float4* a4 = (const float4*)(feats + ((g == 1 ? NS + s : s) * CC) + lane * 12);
        const float4* b4 = (const float4*)((g == 2 ? pbg : pfg) + k * CC + lane * 12);
        float acc = 0.f;
#pragma unroll
        for (int j = 0; j < 3; ++j) {
            float4 a = a4[j], b = b4[j];
            acc += a.x * b.x + a.y * b.y + a.z * b.z + a.w * b.w;
        }
#pragma unroll
        for (int m2 = 1; m2 < 64; m2 <<= 1) acc += __shfl_xor(acc, m2, 64);
        if (lane == 0) dots3[s * 30 + g * 10 + k] = acc;
    }
    __syncthreads();

    if (tid < NS) {
        const float* d = &dots3[tid * 30];
        float maxp = d[0], maxn = d[10];
#pragma unroll
        for (int k = 1; k < KP; ++k) { maxp = fmaxf(maxp, d[k]); maxn = fmaxf(maxn, d[10 + k]); }
        mp[tid] = maxp; mn[tid] = maxn;

        float x[KP], y[KP];
#pragma unroll
        for (int k = 0; k < KP; ++k) { x[k] = d[k] / 0.07f; y[k] = d[20 + k] / 0.07f; }
        float m10 = x[0];
#pragma unroll
        for (int k = 1; k < KP; ++k) m10 = fmaxf(m10, x[k]);
        float se = 0.f;
#pragma unroll
        for (int k = 0; k < KP; ++k) se += expf(x[k] - m10);
        float numer = logf(se) + m10;
        float m20 = m10;
#pragma unroll
        for (int k = 0; k < KP; ++k) m20 = fmaxf(m20, y[k]);
        float se2 = 0.f;
#pragma unroll
        for (int k = 0; k < KP; ++k) se2 += expf(x[k] - m20);
#pragma unroll
        for (int k = 0; k < KP; ++k) se2 += expf(y[k] - m20);
        float denom = logf(se2) + m20;
        infon[tid] = numer - denom;
    }
    __syncthreads();
    if (tid == 0) {
        float sp = 0.f, sn = 0.f, si = 0.f;
        for (int s = 0; s < NS; ++s) { sp += mp[s]; sn += mn[s]; si += infon[s]; }
        sp /= 12.f; sn /= 12.f; si /= 12.f;
        float loss = fmaxf(0.2f + sn - sp, 0.f) + 0.25f * (-si);
        out[0] = loss;
    }
}

// ---------------- K6: blend + renormalize refined prototypes ----------------
__global__ __launch_bounds__(256) void k_blend(const float* __restrict__ fg,
                                               const float* __restrict__ bg,
                                               const float* __restrict__ pfg,
                                               const float* __restrict__ pbg,
                                               float* __restrict__ out) {
    __shared__ float red[256];
    int r = blockIdx.x, tid = threadIdx.x;
    const float* a = (r < 10) ? (fg + r * CC) : (bg + (r - 10) * CC);
    const float* b = (r < 10) ? (pfg + r * CC) : (pbg + (r - 10) * CC);
    float v[3]; float ss = 0.f;
#pragma unroll
    for (int cc = 0; cc < 3; ++cc) {
        int c = tid + cc * 256;
        v[cc] = (1.0f - 0.3f) * a[c] + 0.3f * b[c];
        ss += v[cc] * v[cc];
    }
    red[tid] = ss; __syncthreads();
    for (int off = 128; off > 0; off >>= 1) { if (tid < off) red[tid] += red[tid + off]; __syncthreads(); }
    float inv = 1.f / fmaxf(sqrtf(red[0]), 1e-8f);
    float* o = out + 1 + r * CC;   // fg rows 0..9, bg rows 10..19 are contiguous in out
#pragma unroll
    for (int cc = 0; cc < 3; ++cc) o[tid + cc * 256] = v[cc] * inv;
}

extern "C" void kernel_launch(void* const* d_in, const int* in_sizes, int n_in,
                              void* d_out, int out_size, void* d_ws, size_t ws_size,
                              hipStream_t stream) {
    const float* fg = (const float*)d_in[0];   // [10,768]
    const float* bg = (const float*)d_in[1];   // [10,768]
    const float* F  = (const float*)d_in[2];   // [8,768,64,64]
    const float* M  = (const float*)d_in[3];   // [8,1,64,64]
    float* out = (float*)d_out;                // [1 + 7680 + 7680]

    float* w   = (float*)d_ws;
    float* sfg = w + WS_SCORE_FG;
    float* sbg = w + WS_SCORE_BG;
    int*   sel = (int*)(w + WS_SEL);
    float* fea = w + WS_FEATS;
    float* pfg = w + WS_PFG;
    float* pbg = w + WS_PBG;

    k_scores<<<STOT / 64, 64, 0, stream>>>(fg, bg, F, M, sfg, sbg);
    k_topk  <<<2, 256, 0, stream>>>(w, sel);
    k_gather<<<24, 256, 0, stream>>>(F, sel, fea);
    k_refine<<<2, 256, 0, stream>>>(fea, fg, bg, pfg, pbg);
    k_loss  <<<1, 256, 0, stream>>>(fea, pfg, pbg, out);
    k_blend <<<20, 256, 0, stream>>>(fg, bg, pfg, pbg, out);
}

// Round 3
// 350.627 us; speedup vs baseline: 2.9674x; 1.5137x over previous
//
#include <hip/hip_runtime.h>
#include <math.h>

// Problem constants
#define KP   10      // prototypes per side
#define CC   768     // channels
#define NB   8       // batch
#define HW   4096    // 64*64
#define STOT 32768   // NB*HW
#define NS   12      // N_SAMPLES

// Workspace layout (float offsets)
#define WS_SCORE_FG 0
#define WS_SCORE_BG 32768
#define WS_SEL      65536   // 24 ints
#define WS_FEATS    65600   // 24*768 floats (pos 12 rows, then neg 12 rows)
#define WS_PFG      84032   // 10*768
#define WS_PBG      91712   // 10*768

// ---------------- K1: per-pixel norm + max-sim scores ----------------
// 512-thread blocks: 8 waves x 64 pixels. Wave w accumulates channels
// [96w, 96w+96) for its lane's pixel; LDS reduction across waves.
// 512 blocks x 8 waves = 4096 waves = 16 waves/CU (vs 2 before).
__global__ __launch_bounds__(512) void k_scores(const float* __restrict__ fg,
                                                const float* __restrict__ bg,
                                                const float* __restrict__ F,
                                                const float* __restrict__ M,
                                                float* __restrict__ sfg,
                                                float* __restrict__ sbg) {
    __shared__ float part[8][64][22];
    __shared__ float comb[64][22];

    const int tid  = threadIdx.x;
    const int w    = __builtin_amdgcn_readfirstlane(tid >> 6);  // wave id -> SGPR
    const int lane = tid & 63;
    const int s    = blockIdx.x * 64 + lane;
    const int n    = s >> 12, hw = s & 4095;
    const float* fp = F + ((size_t)n * CC) * HW + hw;
    const int cbase = w * 96;

    float afg[KP], abg[KP], norm2 = 0.f;
#pragma unroll
    for (int k = 0; k < KP; ++k) { afg[k] = 0.f; abg[k] = 0.f; }

    for (int c0 = 0; c0 < 96; c0 += 16) {
        float f[16];
#pragma unroll
        for (int j = 0; j < 16; ++j) f[j] = fp[(size_t)(cbase + c0 + j) * HW];
#pragma unroll
        for (int j = 0; j < 16; ++j) {
            float fv = f[j];
            norm2 = fmaf(fv, fv, norm2);
            const int c = cbase + c0 + j;   // wave-uniform -> scalar loads below
#pragma unroll
            for (int k = 0; k < KP; ++k) afg[k] = fmaf(fv, fg[k * CC + c], afg[k]);
#pragma unroll
            for (int k = 0; k < KP; ++k) abg[k] = fmaf(fv, bg[k * CC + c], abg[k]);
        }
    }

#pragma unroll
    for (int k = 0; k < KP; ++k) { part[w][lane][k] = afg[k]; part[w][lane][10 + k] = abg[k]; }
    part[w][lane][20] = norm2;
    __syncthreads();

    // reduce 8 waves -> comb[pix][j], 64*21 = 1344 items over 512 threads
    for (int item = tid; item < 64 * 21; item += 512) {
        int pix = item / 21, j = item - pix * 21;
        float acc = 0.f;
#pragma unroll
        for (int ww = 0; ww < 8; ++ww) acc += part[ww][pix][j];
        comb[pix][j] = acc;
    }
    __syncthreads();

    if (tid < 64) {
        float mfg = comb[tid][0], mbg = comb[tid][10];
#pragma unroll
        for (int k = 1; k < KP; ++k) { mfg = fmaxf(mfg, comb[tid][k]); mbg = fmaxf(mbg, comb[tid][10 + k]); }
        float nc = fmaxf(sqrtf(comb[tid][20]), 1e-8f);
        int sp = blockIdx.x * 64 + tid;
        float m = fminf(fmaxf(M[sp], 0.f), 1.f);
        sfg[sp] = (1.f - mfg / nc) * m;
        sbg[sp] = (1.f - mbg / nc) * (1.f - m);
    }
}

// ---------------- K2: exact top-12, single pass ----------------
// Per-thread sorted top-12 in registers (static-index unrolled insertion),
// then LDS candidate-pool merge with (value desc, index asc) tie-break.
__global__ __launch_bounds__(256) void k_topk(const float* __restrict__ ws, int* __restrict__ sel) {
    const float* sc = ws + (blockIdx.x == 0 ? WS_SCORE_FG : WS_SCORE_BG);
    int* out = sel + blockIdx.x * NS;
    const int tid = threadIdx.x;
    const int wave = tid >> 6, lane = tid & 63;

    float tv[NS]; int ti[NS];
#pragma unroll
    for (int j = 0; j < NS; ++j) { tv[j] = -1e30f; ti[j] = 0x3fffffff; }

    // Single pass: float4 loads; indices ascend within a thread, so strict-'>'
    // insertion keeps the lowest index on equal values (lax.top_k semantics).
    const float4* sc4 = (const float4*)sc;
    for (int r = 0; r < STOT / 4 / 256; ++r) {   // 32 iterations
        int i4 = r * 256 + tid;
        float4 v4 = sc4[i4];
        float vs[4] = {v4.x, v4.y, v4.z, v4.w};
#pragma unroll
        for (int j = 0; j < 4; ++j) {
            float v = vs[j];
            int idx = i4 * 4 + j;
            if (v > tv[NS - 1]) {
#pragma unroll
                for (int q = NS - 1; q >= 1; --q) {
                    bool shift = v > tv[q - 1];            // insert pos < q: shift down
                    bool here  = !shift && (v > tv[q]);    // insert exactly at q
                    float ntv = shift ? tv[q - 1] : (here ? v : tv[q]);
                    int   nti = shift ? ti[q - 1] : (here ? idx : ti[q]);
                    tv[q] = ntv; ti[q] = nti;
                }
                if (v > tv[0]) { tv[0] = v; ti[0] = idx; }
            }
        }
    }

    // Candidate pool in LDS (stride 13 to avoid 8-way bank conflicts)
    __shared__ float pv[256 * 13];
    __shared__ int   pi[256 * 13];
    __shared__ float rv[4];
    __shared__ int   ri[4];
    __shared__ int   besti_sh;
#pragma unroll
    for (int j = 0; j < NS; ++j) { pv[tid * 13 + j] = tv[j]; pi[tid * 13 + j] = ti[j]; }
    __syncthreads();

    for (int r = 0; r < NS; ++r) {
        // local best over own 12 entries
        float bv = -1e30f; int bi2 = 0x7fffffff;
#pragma unroll
        for (int j = 0; j < NS; ++j) {
            float v = pv[tid * 13 + j]; int idx = pi[tid * 13 + j];
            if (v > bv || (v == bv && idx < bi2)) { bv = v; bi2 = idx; }
        }
        // wave reduce with tie-break
#pragma unroll
        for (int m2 = 1; m2 < 64; m2 <<= 1) {
            float ov = __shfl_xor(bv, m2, 64);
            int   oi = __shfl_xor(bi2, m2, 64);
            if (ov > bv || (ov == bv && oi < bi2)) { bv = ov; bi2 = oi; }
        }
        if (lane == 0) { rv[wave] = bv; ri[wave] = bi2; }
        __syncthreads();
        if (tid == 0) {
            float fb = rv[0]; int fi = ri[0];
#pragma unroll
            for (int w2 = 1; w2 < 4; ++w2) {
                if (rv[w2] > fb || (rv[w2] == fb && ri[w2] < fi)) { fb = rv[w2]; fi = ri[w2]; }
            }
            out[r] = fi;
            besti_sh = fi;
        }
        __syncthreads();
        int fi = besti_sh;
        // each pixel index lives in exactly one thread's pool -> clear own copy
#pragma unroll
        for (int j = 0; j < NS; ++j) {
            if (pi[tid * 13 + j] == fi) pv[tid * 13 + j] = -1e30f;
        }
        __syncthreads();
    }
}

// ---------------- K3: gather selected pixels + normalize ----------------
__global__ __launch_bounds__(256) void k_gather(const float* __restrict__ F,
                                                const int* __restrict__ sel,
                                                float* __restrict__ feats) {
    int b = blockIdx.x;                  // 0..23
    int s = sel[b];
    int n = s >> 12, hw = s & 4095;
    const float* fp = F + ((size_t)n * CC) * HW + hw;
    int tid = threadIdx.x;

    float v0 = fp[(size_t)(tid)       * HW];
    float v1 = fp[(size_t)(tid + 256) * HW];
    float v2 = fp[(size_t)(tid + 512) * HW];
    __shared__ float red[256];
    red[tid] = v0 * v0 + v1 * v1 + v2 * v2;
    __syncthreads();
    for (int off = 128; off > 0; off >>= 1) { if (tid < off) red[tid] += red[tid + off]; __syncthreads(); }
    float inv = 1.f / fmaxf(sqrtf(red[0]), 1e-8f);
    feats[b * CC + tid]       = v0 * inv;
    feats[b * CC + tid + 256] = v1 * inv;
    feats[b * CC + tid + 512] = v2 * inv;
}

// ---------------- K4: iterative refinement (block 0: fg, block 1: bg) ----------------
__global__ __launch_bounds__(256) void k_refine(const float* __restrict__ feats_all,
                                                const float* __restrict__ fg,
                                                const float* __restrict__ bg,
                                                float* __restrict__ pfg,
                                                float* __restrict__ pbg) {
    __shared__ float fe[NS * CC];
    __shared__ float pp[KP * CC];
    __shared__ float tmp[KP * CC];
    __shared__ float dots[NS * KP];
    __shared__ int   assign[NS];
    __shared__ float cntf[KP];
    __shared__ float red[256 * KP];
    __shared__ float nrm[KP];

    const int tid = threadIdx.x;
    const float* feats = feats_all + blockIdx.x * (NS * CC);
    const float* p0    = (blockIdx.x == 0) ? fg : bg;
    float* pout        = (blockIdx.x == 0) ? pfg : pbg;

    for (int i = tid; i < NS * CC; i += 256) fe[i] = feats[i];
    for (int i = tid; i < KP * CC; i += 256) pp[i] = p0[i];
    __syncthreads();

    const int wave = tid >> 6, lane = tid & 63;

    for (int it = 0; it < 10; ++it) {
        float step = 0.1f / (1.0f + 0.5f * (float)it);

        // dots[s][k] = <fe_s, pp_k> ; one wave per (s,k) pair
        for (int pid = wave; pid < NS * KP; pid += 4) {
            int s = pid / KP, k = pid % KP;
            const float4* fr = (const float4*)&fe[s * CC + lane * 12];
            const float4* pr = (const float4*)&pp[k * CC + lane * 12];
            float acc = 0.f;
#pragma unroll
            for (int j = 0; j < 3; ++j) {
                float4 a = fr[j], b = pr[j];
                acc += a.x * b.x + a.y * b.y + a.z * b.z + a.w * b.w;
            }
#pragma unroll
            for (int m2 = 1; m2 < 64; m2 <<= 1) acc += __shfl_xor(acc, m2, 64);
            if (lane == 0) dots[s * KP + k] = acc;
        }
        __syncthreads();

        if (tid < NS) {
            int best = 0; float bvv = dots[tid * KP];
#pragma unroll
            for (int k = 1; k < KP; ++k) { float v = dots[tid * KP + k]; if (v > bvv) { bvv = v; best = k; } }
            assign[tid] = best;
        }
        __syncthreads();
        if (tid < KP) {
            int c = 0;
            for (int s = 0; s < NS; ++s) c += (assign[s] == tid);
            cntf[tid] = (float)c;
        }
        __syncthreads();

        // blend + accumulate row sums of squares
        float ss[KP];
#pragma unroll
        for (int k = 0; k < KP; ++k) ss[k] = 0.f;
        for (int cc = 0; cc < 3; ++cc) {
            int c = tid + cc * 256;
            float acc[KP];
#pragma unroll
            for (int k = 0; k < KP; ++k) acc[k] = 0.f;
            for (int s = 0; s < NS; ++s) {
                int a = assign[s];
                float v = fe[s * CC + c];
#pragma unroll
                for (int k = 0; k < KP; ++k) acc[k] += (a == k) ? v : 0.f;
            }
#pragma unroll
            for (int k = 0; k < KP; ++k) {
                float mean = acc[k] / fmaxf(cntf[k], 1.0f);
                float v = (1.0f - step) * pp[k * CC + c] + step * mean;
                tmp[k * CC + c] = v;
                ss[k] += v * v;
            }
        }
#pragma unroll
        for (int k = 0; k < KP; ++k) red[tid * KP + k] = ss[k];
        __syncthreads();
        for (int off = 128; off > 0; off >>= 1) {
            if (tid < off) {
#pragma unroll
                for (int k = 0; k < KP; ++k) red[tid * KP + k] += red[(tid + off) * KP + k];
            }
            __syncthreads();
        }
        if (tid < KP) nrm[tid] = sqrtf(red[tid]);
        __syncthreads();
        for (int cc = 0; cc < 3; ++cc) {
            int c = tid + cc * 256;
#pragma unroll
            for (int k = 0; k < KP; ++k) {
                if (cntf[k] > 0.f) pp[k * CC + c] = tmp[k * CC + c] / fmaxf(nrm[k], 1e-8f);
            }
        }
        __syncthreads();
    }
    for (int i = tid; i < KP * CC; i += 256) pout[i] = pp[i];
}

// ---------------- K5: triplet + InfoNCE loss ----------------
__global__ __launch_bounds__(256) void k_loss(const float* __restrict__ feats,
                                              const float* __restrict__ pfg,
                                              const float* __restrict__ pbg,
                                              float* __restrict__ out) {
    __shared__ float dots3[NS * 30];   // [s][g*10+k]: g=0 pos@pfg, g=1 neg@pfg, g=2 pos@pbg
    __shared__ float mp[NS], mn[NS], infon[NS];
    int tid = threadIdx.x, wave = tid >> 6, lane = tid & 63;

    for (int pid = wave; pid < 360; pid += 4) {
        int g = pid / 120, r = pid % 120, s = r / KP, k = r % KP;
        const float4* a4 = (const float4*)(feats + ((g == 1 ? NS + s : s) * CC) + lane * 12);
        const float4* b4 = (const float4*)((g == 2 ? pbg : pfg) + k * CC + lane * 12);
        float acc = 0.f;
#pragma unroll
        for (int j = 0; j < 3; ++j) {
            float4 a = a4[j], b = b4[j];
            acc += a.x * b.x + a.y * b.y + a.z * b.z + a.w * b.w;
        }
#pragma unroll
        for (int m2 = 1; m2 < 64; m2 <<= 1) acc += __shfl_xor(acc, m2, 64);
        if (lane == 0) dots3[s * 30 + g * 10 + k] = acc;
    }
    __syncthreads();

    if (tid < NS) {
        const float* d = &dots3[tid * 30];
        float maxp = d[0], maxn = d[10];
#pragma unroll
        for (int k = 1; k < KP; ++k) { maxp = fmaxf(maxp, d[k]); maxn = fmaxf(maxn, d[10 + k]); }
        mp[tid] = maxp; mn[tid] = maxn;

        float x[KP], y[KP];
#pragma unroll
        for (int k = 0; k < KP; ++k) { x[k] = d[k] / 0.07f; y[k] = d[20 + k] / 0.07f; }
        float m10 = x[0];
#pragma unroll
        for (int k = 1; k < KP; ++k) m10 = fmaxf(m10, x[k]);
        float se = 0.f;
#pragma unroll
        for (int k = 0; k < KP; ++k) se += expf(x[k] - m10);
        float numer = logf(se) + m10;
        float m20 = m10;
#pragma unroll
        for (int k = 0; k < KP; ++k) m20 = fmaxf(m20, y[k]);
        float se2 = 0.f;
#pragma unroll
        for (int k = 0; k < KP; ++k) se2 += expf(x[k] - m20);
#pragma unroll
        for (int k = 0; k < KP; ++k) se2 += expf(y[k] - m20);
        float denom = logf(se2) + m20;
        infon[tid] = numer - denom;
    }
    __syncthreads();
    if (tid == 0) {
        float sp = 0.f, sn = 0.f, si = 0.f;
        for (int s = 0; s < NS; ++s) { sp += mp[s]; sn += mn[s]; si += infon[s]; }
        sp /= 12.f; sn /= 12.f; si /= 12.f;
        float loss = fmaxf(0.2f + sn - sp, 0.f) + 0.25f * (-si);
        out[0] = loss;
    }
}

// ---------------- K6: blend + renormalize refined prototypes ----------------
__global__ __launch_bounds__(256) void k_blend(const float* __restrict__ fg,
                                               const float* __restrict__ bg,
                                               const float* __restrict__ pfg,
                                               const float* __restrict__ pbg,
                                               float* __restrict__ out) {
    __shared__ float red[256];
    int r = blockIdx.x, tid = threadIdx.x;
    const float* a = (r < 10) ? (fg + r * CC) : (bg + (r - 10) * CC);
    const float* b = (r < 10) ? (pfg + r * CC) : (pbg + (r - 10) * CC);
    float v[3]; float ss = 0.f;
#pragma unroll
    for (int cc = 0; cc < 3; ++cc) {
        int c = tid + cc * 256;
        v[cc] = (1.0f - 0.3f) * a[c] + 0.3f * b[c];
        ss += v[cc] * v[cc];
    }
    red[tid] = ss; __syncthreads();
    for (int off = 128; off > 0; off >>= 1) { if (tid < off) red[tid] += red[tid + off]; __syncthreads(); }
    float inv = 1.f / fmaxf(sqrtf(red[0]), 1e-8f);
    float* o = out + 1 + r * CC;   // fg rows 0..9, bg rows 10..19 are contiguous in out
#pragma unroll
    for (int cc = 0; cc < 3; ++cc) o[tid + cc * 256] = v[cc] * inv;
}

extern "C" void kernel_launch(void* const* d_in, const int* in_sizes, int n_in,
                              void* d_out, int out_size, void* d_ws, size_t ws_size,
                              hipStream_t stream) {
    const float* fg = (const float*)d_in[0];   // [10,768]
    const float* bg = (const float*)d_in[1];   // [10,768]
    const float* F  = (const float*)d_in[2];   // [8,768,64,64]
    const float* M  = (const float*)d_in[3];   // [8,1,64,64]
    float* out = (float*)d_out;                // [1 + 7680 + 7680]

    float* w   = (float*)d_ws;
    float* sfg = w + WS_SCORE_FG;
    float* sbg = w + WS_SCORE_BG;
    int*   sel = (int*)(w + WS_SEL);
    float* fea = w + WS_FEATS;
    float* pfg = w + WS_PFG;
    float* pbg = w + WS_PBG;

    k_scores<<<512, 512, 0, stream>>>(fg, bg, F, M, sfg, sbg);
    k_topk  <<<2, 256, 0, stream>>>(w, sel);
    k_gather<<<24, 256, 0, stream>>>(F, sel, fea);
    k_refine<<<2, 256, 0, stream>>>(fea, fg, bg, pfg, pbg);
    k_loss  <<<1, 256, 0, stream>>>(fea, pfg, pbg, out);
    k_blend <<<20, 256, 0, stream>>>(fg, bg, pfg, pbg, out);
}

// Round 4
// 214.223 us; speedup vs baseline: 4.8569x; 1.6367x over previous
//
#include <hip/hip_runtime.h>
#include <math.h>

// Problem constants
#define KP   10      // prototypes per side
#define CC   768     // channels
#define NB   8       // batch
#define HW   4096    // 64*64
#define STOT 32768   // NB*HW
#define NS   12      // N_SAMPLES

// Workspace layout (float offsets)
#define WS_SCORE_FG 0
#define WS_SCORE_BG 32768
#define WS_SEL      65536   // 24 ints
#define WS_FEATS    65600   // 24*768 floats (pos 12 rows, then neg 12 rows)
#define WS_PFG      84032   // 10*768
#define WS_PBG      91712   // 10*768

// ---------------- K1: per-pixel norm + max-sim scores ----------------
// 512-thread blocks: 8 waves x 64 pixels. Wave w accumulates channels
// [96w, 96w+96) for its lane's pixel; LDS reduction across waves.
__global__ __launch_bounds__(512) void k_scores(const float* __restrict__ fg,
                                                const float* __restrict__ bg,
                                                const float* __restrict__ F,
                                                const float* __restrict__ M,
                                                float* __restrict__ sfg,
                                                float* __restrict__ sbg) {
    __shared__ float part[8][64][22];
    __shared__ float comb[64][22];

    const int tid  = threadIdx.x;
    const int w    = __builtin_amdgcn_readfirstlane(tid >> 6);  // wave id -> SGPR
    const int lane = tid & 63;
    const int s    = blockIdx.x * 64 + lane;
    const int n    = s >> 12, hw = s & 4095;
    const float* fp = F + ((size_t)n * CC) * HW + hw;
    const int cbase = w * 96;

    float afg[KP], abg[KP], norm2 = 0.f;
#pragma unroll
    for (int k = 0; k < KP; ++k) { afg[k] = 0.f; abg[k] = 0.f; }

    for (int c0 = 0; c0 < 96; c0 += 16) {
        float f[16];
#pragma unroll
        for (int j = 0; j < 16; ++j) f[j] = fp[(size_t)(cbase + c0 + j) * HW];
#pragma unroll
        for (int j = 0; j < 16; ++j) {
            float fv = f[j];
            norm2 = fmaf(fv, fv, norm2);
            const int c = cbase + c0 + j;   // wave-uniform -> scalar loads below
#pragma unroll
            for (int k = 0; k < KP; ++k) afg[k] = fmaf(fv, fg[k * CC + c], afg[k]);
#pragma unroll
            for (int k = 0; k < KP; ++k) abg[k] = fmaf(fv, bg[k * CC + c], abg[k]);
        }
    }

#pragma unroll
    for (int k = 0; k < KP; ++k) { part[w][lane][k] = afg[k]; part[w][lane][10 + k] = abg[k]; }
    part[w][lane][20] = norm2;
    __syncthreads();

    // reduce 8 waves -> comb[pix][j], 64*21 = 1344 items over 512 threads
    for (int item = tid; item < 64 * 21; item += 512) {
        int pix = item / 21, j = item - pix * 21;
        float acc = 0.f;
#pragma unroll
        for (int ww = 0; ww < 8; ++ww) acc += part[ww][pix][j];
        comb[pix][j] = acc;
    }
    __syncthreads();

    if (tid < 64) {
        float mfg = comb[tid][0], mbg = comb[tid][10];
#pragma unroll
        for (int k = 1; k < KP; ++k) { mfg = fmaxf(mfg, comb[tid][k]); mbg = fmaxf(mbg, comb[tid][10 + k]); }
        float nc = fmaxf(sqrtf(comb[tid][20]), 1e-8f);
        int sp = blockIdx.x * 64 + tid;
        float m = fminf(fmaxf(M[sp], 0.f), 1.f);
        sfg[sp] = (1.f - mfg / nc) * m;
        sbg[sp] = (1.f - mbg / nc) * (1.f - m);
    }
}

// ---------------- K2: exact top-12, single pass ----------------
__global__ __launch_bounds__(256) void k_topk(const float* __restrict__ ws, int* __restrict__ sel) {
    const float* sc = ws + (blockIdx.x == 0 ? WS_SCORE_FG : WS_SCORE_BG);
    int* out = sel + blockIdx.x * NS;
    const int tid = threadIdx.x;
    const int wave = tid >> 6, lane = tid & 63;

    float tv[NS]; int ti[NS];
#pragma unroll
    for (int j = 0; j < NS; ++j) { tv[j] = -1e30f; ti[j] = 0x3fffffff; }

    const float4* sc4 = (const float4*)sc;
    for (int r = 0; r < STOT / 4 / 256; ++r) {   // 32 iterations
        int i4 = r * 256 + tid;
        float4 v4 = sc4[i4];
        float vs[4] = {v4.x, v4.y, v4.z, v4.w};
#pragma unroll
        for (int j = 0; j < 4; ++j) {
            float v = vs[j];
            int idx = i4 * 4 + j;
            if (v > tv[NS - 1]) {
#pragma unroll
                for (int q = NS - 1; q >= 1; --q) {
                    bool shift = v > tv[q - 1];
                    bool here  = !shift && (v > tv[q]);
                    float ntv = shift ? tv[q - 1] : (here ? v : tv[q]);
                    int   nti = shift ? ti[q - 1] : (here ? idx : ti[q]);
                    tv[q] = ntv; ti[q] = nti;
                }
                if (v > tv[0]) { tv[0] = v; ti[0] = idx; }
            }
        }
    }

    __shared__ float pv[256 * 13];
    __shared__ int   pi[256 * 13];
    __shared__ float rv[4];
    __shared__ int   ri[4];
    __shared__ int   besti_sh;
#pragma unroll
    for (int j = 0; j < NS; ++j) { pv[tid * 13 + j] = tv[j]; pi[tid * 13 + j] = ti[j]; }
    __syncthreads();

    for (int r = 0; r < NS; ++r) {
        float bv = -1e30f; int bi2 = 0x7fffffff;
#pragma unroll
        for (int j = 0; j < NS; ++j) {
            float v = pv[tid * 13 + j]; int idx = pi[tid * 13 + j];
            if (v > bv || (v == bv && idx < bi2)) { bv = v; bi2 = idx; }
        }
#pragma unroll
        for (int m2 = 1; m2 < 64; m2 <<= 1) {
            float ov = __shfl_xor(bv, m2, 64);
            int   oi = __shfl_xor(bi2, m2, 64);
            if (ov > bv || (ov == bv && oi < bi2)) { bv = ov; bi2 = oi; }
        }
        if (lane == 0) { rv[wave] = bv; ri[wave] = bi2; }
        __syncthreads();
        if (tid == 0) {
            float fb = rv[0]; int fi = ri[0];
#pragma unroll
            for (int w2 = 1; w2 < 4; ++w2) {
                if (rv[w2] > fb || (rv[w2] == fb && ri[w2] < fi)) { fb = rv[w2]; fi = ri[w2]; }
            }
            out[r] = fi;
            besti_sh = fi;
        }
        __syncthreads();
        int fi = besti_sh;
#pragma unroll
        for (int j = 0; j < NS; ++j) {
            if (pi[tid * 13 + j] == fi) pv[tid * 13 + j] = -1e30f;
        }
        __syncthreads();
    }
}

// ---------------- K3: gather selected pixels + normalize ----------------
__global__ __launch_bounds__(256) void k_gather(const float* __restrict__ F,
                                                const int* __restrict__ sel,
                                                float* __restrict__ feats) {
    int b = blockIdx.x;                  // 0..23
    int s = sel[b];
    int n = s >> 12, hw = s & 4095;
    const float* fp = F + ((size_t)n * CC) * HW + hw;
    int tid = threadIdx.x;

    float v0 = fp[(size_t)(tid)       * HW];
    float v1 = fp[(size_t)(tid + 256) * HW];
    float v2 = fp[(size_t)(tid + 512) * HW];
    __shared__ float red[256];
    red[tid] = v0 * v0 + v1 * v1 + v2 * v2;
    __syncthreads();
    for (int off = 128; off > 0; off >>= 1) { if (tid < off) red[tid] += red[tid + off]; __syncthreads(); }
    float inv = 1.f / fmaxf(sqrtf(red[0]), 1e-8f);
    feats[b * CC + tid]       = v0 * inv;
    feats[b * CC + tid + 256] = v1 * inv;
    feats[b * CC + tid + 512] = v2 * inv;
}

// ---------------- K4: refinement, one wave per prototype ----------------
// 640 threads = 10 waves. Wave k owns prototype k in 12 VGPRs (lane l holds
// channels l+64j). fe in LDS, stride-1 conflict-free reads. 2 barriers/iter.
__global__ __launch_bounds__(640) void k_refine(const float* __restrict__ feats_all,
                                                const float* __restrict__ fg,
                                                const float* __restrict__ bg,
                                                float* __restrict__ pfg,
                                                float* __restrict__ pbg) {
    __shared__ float fe[NS * CC];
    __shared__ float dots[NS][KP];
    __shared__ int   assign[NS];

    const int tid  = threadIdx.x;
    const int k    = __builtin_amdgcn_readfirstlane(tid >> 6);   // wave id = proto id
    const int lane = tid & 63;
    const float* feats = feats_all + blockIdx.x * (NS * CC);
    const float* p0    = (blockIdx.x == 0) ? fg : bg;
    float* pout        = (blockIdx.x == 0) ? pfg : pbg;

    for (int i = tid; i < NS * CC; i += 640) fe[i] = feats[i];
    float p[12];
#pragma unroll
    for (int j = 0; j < 12; ++j) p[j] = p0[k * CC + j * 64 + lane];
    __syncthreads();

    for (int it = 0; it < 10; ++it) {
        float step = 0.1f / (1.0f + 0.5f * (float)it);

        // d[s] = <fe_s, p_k>
        float d[NS];
#pragma unroll
        for (int s = 0; s < NS; ++s) d[s] = 0.f;
#pragma unroll
        for (int j = 0; j < 12; ++j) {
            float pvj = p[j];
#pragma unroll
            for (int s = 0; s < NS; ++s) d[s] = fmaf(fe[s * CC + j * 64 + lane], pvj, d[s]);
        }
#pragma unroll
        for (int s = 0; s < NS; ++s) {
#pragma unroll
            for (int m2 = 1; m2 < 64; m2 <<= 1) d[s] += __shfl_xor(d[s], m2, 64);
        }
        if (lane == 0) {
#pragma unroll
            for (int s = 0; s < NS; ++s) dots[s][k] = d[s];
        }
        __syncthreads();

        if (tid < NS) {
            float bv = dots[tid][0]; int bk = 0;
#pragma unroll
            for (int kk = 1; kk < KP; ++kk) { float v = dots[tid][kk]; if (v > bv) { bv = v; bk = kk; } }
            assign[tid] = bk;
        }
        __syncthreads();

        int a[NS]; int cnt = 0;
#pragma unroll
        for (int s = 0; s < NS; ++s) { a[s] = assign[s]; cnt += (a[s] == k) ? 1 : 0; }

        if (cnt > 0) {
            float mac[12];
#pragma unroll
            for (int j = 0; j < 12; ++j) mac[j] = 0.f;
#pragma unroll
            for (int s = 0; s < NS; ++s) {
                if (a[s] == k) {   // wave-uniform branch
#pragma unroll
                    for (int j = 0; j < 12; ++j) mac[j] += fe[s * CC + j * 64 + lane];
                }
            }
            float fcnt = (float)cnt;
            float v[12]; float ss = 0.f;
#pragma unroll
            for (int j = 0; j < 12; ++j) {
                float mean = mac[j] / fcnt;
                v[j] = (1.0f - step) * p[j] + step * mean;
                ss = fmaf(v[j], v[j], ss);
            }
#pragma unroll
            for (int m2 = 1; m2 < 64; m2 <<= 1) ss += __shfl_xor(ss, m2, 64);
            float inv = 1.f / fmaxf(sqrtf(ss), 1e-8f);
#pragma unroll
            for (int j = 0; j < 12; ++j) p[j] = v[j] * inv;
        }
    }

#pragma unroll
    for (int j = 0; j < 12; ++j) pout[k * CC + j * 64 + lane] = p[j];
}

// ---------------- K5: triplet + InfoNCE loss ----------------
__global__ __launch_bounds__(256) void k_loss(const float* __restrict__ feats,
                                              const float* __restrict__ pfg,
                                              const float* __restrict__ pbg,
                                              float* __restrict__ out) {
    __shared__ float dots3[NS * 30];   // [s][g*10+k]: g=0 pos@pfg, g=1 neg@pfg, g=2 pos@pbg
    __shared__ float mp[NS], mn[NS], infon[NS];
    int tid = threadIdx.x, wave = tid >> 6, lane = tid & 63;

    for (int pid = wave; pid < 360; pid += 4) {
        int g = pid / 120, r = pid % 120, s = r / KP, k = r % KP;
        const float4* a4 = (const float4*)(feats + ((g == 1 ? NS + s : s) * CC) + lane * 12);
        const float4* b4 = (const float4*)((g == 2 ? pbg : pfg) + k * CC + lane * 12);
        float acc = 0.f;
#pragma unroll
        for (int j = 0; j < 3; ++j) {
            float4 a = a4[j], b = b4[j];
            acc += a.x * b.x + a.y * b.y + a.z * b.z + a.w * b.w;
        }
#pragma unroll
        for (int m2 = 1; m2 < 64; m2 <<= 1) acc += __shfl_xor(acc, m2, 64);
        if (lane == 0) dots3[s * 30 + g * 10 + k] = acc;
    }
    __syncthreads();

    if (tid < NS) {
        const float* d = &dots3[tid * 30];
        float maxp = d[0], maxn = d[10];
#pragma unroll
        for (int k = 1; k < KP; ++k) { maxp = fmaxf(maxp, d[k]); maxn = fmaxf(maxn, d[10 + k]); }
        mp[tid] = maxp; mn[tid] = maxn;

        float x[KP], y[KP];
#pragma unroll
        for (int k = 0; k < KP; ++k) { x[k] = d[k] / 0.07f; y[k] = d[20 + k] / 0.07f; }
        float m10 = x[0];
#pragma unroll
        for (int k = 1; k < KP; ++k) m10 = fmaxf(m10, x[k]);
        float se = 0.f;
#pragma unroll
        for (int k = 0; k < KP; ++k) se += expf(x[k] - m10);
        float numer = logf(se) + m10;
        float m20 = m10;
#pragma unroll
        for (int k = 0; k < KP; ++k) m20 = fmaxf(m20, y[k]);
        float se2 = 0.f;
#pragma unroll
        for (int k = 0; k < KP; ++k) se2 += expf(x[k] - m20);
#pragma unroll
        for (int k = 0; k < KP; ++k) se2 += expf(y[k] - m20);
        float denom = logf(se2) + m20;
        infon[tid] = numer - denom;
    }
    __syncthreads();
    if (tid == 0) {
        float sp = 0.f, sn = 0.f, si = 0.f;
        for (int s = 0; s < NS; ++s) { sp += mp[s]; sn += mn[s]; si += infon[s]; }
        sp /= 12.f; sn /= 12.f; si /= 12.f;
        float loss = fmaxf(0.2f + sn - sp, 0.f) + 0.25f * (-si);
        out[0] = loss;
    }
}

// ---------------- K6: blend + renormalize refined prototypes ----------------
__global__ __launch_bounds__(256) void k_blend(const float* __restrict__ fg,
                                               const float* __restrict__ bg,
                                               const float* __restrict__ pfg,
                                               const float* __restrict__ pbg,
                                               float* __restrict__ out) {
    __shared__ float red[256];
    int r = blockIdx.x, tid = threadIdx.x;
    const float* a = (r < 10) ? (fg + r * CC) : (bg + (r - 10) * CC);
    const float* b = (r < 10) ? (pfg + r * CC) : (pbg + (r - 10) * CC);
    float v[3]; float ss = 0.f;
#pragma unroll
    for (int cc = 0; cc < 3; ++cc) {
        int c = tid + cc * 256;
        v[cc] = (1.0f - 0.3f) * a[c] + 0.3f * b[c];
        ss += v[cc] * v[cc];
    }
    red[tid] = ss; __syncthreads();
    for (int off = 128; off > 0; off >>= 1) { if (tid < off) red[tid] += red[tid + off]; __syncthreads(); }
    float inv = 1.f / fmaxf(sqrtf(red[0]), 1e-8f);
    float* o = out + 1 + r * CC;   // fg rows 0..9, bg rows 10..19 are contiguous in out
#pragma unroll
    for (int cc = 0; cc < 3; ++cc) o[tid + cc * 256] = v[cc] * inv;
}

extern "C" void kernel_launch(void* const* d_in, const int* in_sizes, int n_in,
                              void* d_out, int out_size, void* d_ws, size_t ws_size,
                              hipStream_t stream) {
    const float* fg = (const float*)d_in[0];   // [10,768]
    const float* bg = (const float*)d_in[1];   // [10,768]
    const float* F  = (const float*)d_in[2];   // [8,768,64,64]
    const float* M  = (const float*)d_in[3];   // [8,1,64,64]
    float* out = (float*)d_out;                // [1 + 7680 + 7680]

    float* w   = (float*)d_ws;
    float* sfg = w + WS_SCORE_FG;
    float* sbg = w + WS_SCORE_BG;
    int*   sel = (int*)(w + WS_SEL);
    float* fea = w + WS_FEATS;
    float* pfg = w + WS_PFG;
    float* pbg = w + WS_PBG;

    k_scores<<<512, 512, 0, stream>>>(fg, bg, F, M, sfg, sbg);
    k_topk  <<<2, 256, 0, stream>>>(w, sel);
    k_gather<<<24, 256, 0, stream>>>(F, sel, fea);
    k_refine<<<2, 640, 0, stream>>>(fea, fg, bg, pfg, pbg);
    k_loss  <<<1, 256, 0, stream>>>(fea, pfg, pbg, out);
    k_blend <<<20, 256, 0, stream>>>(fg, bg, pfg, pbg, out);
}

// Round 5
// 180.062 us; speedup vs baseline: 5.7784x; 1.1897x over previous
//
#include <hip/hip_runtime.h>
#include <math.h>

// Problem constants
#define KP   10      // prototypes per side
#define CC   768     // channels
#define NB   8       // batch
#define HW   4096    // 64*64
#define STOT 32768   // NB*HW
#define NS   12      // N_SAMPLES

// Workspace layout (float offsets)
#define WS_SCORE_FG 0
#define WS_SCORE_BG 32768
#define WS_SEL      65536   // 24 ints
#define WS_FEATS    65600   // 24*768 floats (pos 12 rows, then neg 12 rows)
#define WS_PFG      84032   // 10*768
#define WS_PBG      91712   // 10*768
// top-k candidates (2 sides x 384 u64) overlap WS_PFG: written by k_topk1,
// read by k_topk2, and only later clobbered by k_refine's pfg output. Safe.
#define WS_CAND     84032

typedef unsigned long long ull;

// ---------------- K1: per-pixel norm + max-sim scores ----------------
// 512-thread blocks: 8 waves x 64 pixels. Wave w accumulates channels
// [96w, 96w+96). Protos read via FORCED vector loads (uniform address +
// opaque zero) to avoid the SGPR-starved s_load serial chain.
__global__ __launch_bounds__(512, 4) void k_scores(const float* __restrict__ fg,
                                                   const float* __restrict__ bg,
                                                   const float* __restrict__ F,
                                                   const float* __restrict__ M,
                                                   float* __restrict__ sfg,
                                                   float* __restrict__ sbg) {
    __shared__ float part[8][64][23];
    __shared__ float comb[64][23];

    const int tid  = threadIdx.x;
    const int w    = __builtin_amdgcn_readfirstlane(tid >> 6);  // wave id -> SGPR
    const int lane = tid & 63;
    const int s    = blockIdx.x * 64 + lane;
    const int n    = s >> 12, hw = s & 4095;
    const float* fp = F + ((size_t)n * CC) * HW + hw;
    const int cbase = w * 96;

    int z;  // opaque zero in a VGPR: keeps proto addresses on the vector path
    asm volatile("v_mov_b32 %0, 0" : "=v"(z));

    float afg[KP], abg[KP], norm2 = 0.f;
#pragma unroll
    for (int k = 0; k < KP; ++k) { afg[k] = 0.f; abg[k] = 0.f; }

    for (int c0 = 0; c0 < 96; c0 += 8) {
        float f[8];
#pragma unroll
        for (int j = 0; j < 8; ++j) f[j] = fp[(size_t)(cbase + c0 + j) * HW];

#pragma unroll
        for (int k = 0; k < KP; ++k) {
            const float4* pq = (const float4*)(fg + k * CC + cbase + c0 + z);
            float4 a = pq[0], b = pq[1];
            float acc = afg[k];
            acc = fmaf(f[0], a.x, acc); acc = fmaf(f[1], a.y, acc);
            acc = fmaf(f[2], a.z, acc); acc = fmaf(f[3], a.w, acc);
            acc = fmaf(f[4], b.x, acc); acc = fmaf(f[5], b.y, acc);
            acc = fmaf(f[6], b.z, acc); acc = fmaf(f[7], b.w, acc);
            afg[k] = acc;
        }
#pragma unroll
        for (int k = 0; k < KP; ++k) {
            const float4* pq = (const float4*)(bg + k * CC + cbase + c0 + z);
            float4 a = pq[0], b = pq[1];
            float acc = abg[k];
            acc = fmaf(f[0], a.x, acc); acc = fmaf(f[1], a.y, acc);
            acc = fmaf(f[2], a.z, acc); acc = fmaf(f[3], a.w, acc);
            acc = fmaf(f[4], b.x, acc); acc = fmaf(f[5], b.y, acc);
            acc = fmaf(f[6], b.z, acc); acc = fmaf(f[7], b.w, acc);
            abg[k] = acc;
        }
#pragma unroll
        for (int j = 0; j < 8; ++j) norm2 = fmaf(f[j], f[j], norm2);
    }

#pragma unroll
    for (int k = 0; k < KP; ++k) { part[w][lane][k] = afg[k]; part[w][lane][10 + k] = abg[k]; }
    part[w][lane][20] = norm2;
    __syncthreads();

    // reduce 8 waves -> comb[pix][j], 64*21 = 1344 items over 512 threads
    for (int item = tid; item < 64 * 21; item += 512) {
        int pix = item / 21, j = item - pix * 21;
        float acc = 0.f;
#pragma unroll
        for (int ww = 0; ww < 8; ++ww) acc += part[ww][pix][j];
        comb[pix][j] = acc;
    }
    __syncthreads();

    if (tid < 64) {
        float mfg = comb[tid][0], mbg = comb[tid][10];
#pragma unroll
        for (int k = 1; k < KP; ++k) { mfg = fmaxf(mfg, comb[tid][k]); mbg = fmaxf(mbg, comb[tid][10 + k]); }
        float nc = fmaxf(sqrtf(comb[tid][20]), 1e-8f);
        int sp = blockIdx.x * 64 + tid;
        float m = fminf(fmaxf(M[sp], 0.f), 1.f);
        sfg[sp] = (1.f - mfg / nc) * m;
        sbg[sp] = (1.f - mbg / nc) * (1.f - m);
    }
}

// Order-preserving float->uint map, packed with ~index for exact
// (value desc, index asc) ordering under unsigned max.
__device__ __forceinline__ ull pack_key(float v, int idx) {
    unsigned u = __float_as_uint(v);
    u ^= (unsigned)((int)u >> 31) | 0x80000000u;
    return ((ull)u << 32) | (ull)(0xFFFFFFFFu - (unsigned)idx);
}

// ---------------- K2a: top-12 stage 1 (64 blocks: 32 per side) ----------------
__global__ __launch_bounds__(256) void k_topk1(const float* __restrict__ ws,
                                               ull* __restrict__ cand) {
    const int side = blockIdx.x >> 5, blk = blockIdx.x & 31;
    const float4* sc4 = (const float4*)(ws + (side == 0 ? WS_SCORE_FG : WS_SCORE_BG));
    const int tid = threadIdx.x;
    const int wave = tid >> 6, lane = tid & 63;

    const int i4 = blk * 256 + tid;
    float4 v4 = sc4[i4];
    ull kk[4];
    kk[0] = pack_key(v4.x, 4 * i4 + 0);
    kk[1] = pack_key(v4.y, 4 * i4 + 1);
    kk[2] = pack_key(v4.z, 4 * i4 + 2);
    kk[3] = pack_key(v4.w, 4 * i4 + 3);

    __shared__ ull wbest[4];
    __shared__ ull win_sh;

    for (int r = 0; r < NS; ++r) {
        ull b = kk[0];
#pragma unroll
        for (int q = 1; q < 4; ++q) b = (kk[q] > b) ? kk[q] : b;
#pragma unroll
        for (int m2 = 1; m2 < 64; m2 <<= 1) {
            ull o = __shfl_xor(b, m2, 64);
            b = (o > b) ? o : b;
        }
        if (lane == 0) wbest[wave] = b;
        __syncthreads();
        if (tid == 0) {
            ull m = wbest[0];
#pragma unroll
            for (int ww = 1; ww < 4; ++ww) m = (wbest[ww] > m) ? wbest[ww] : m;
            win_sh = m;
            cand[side * 384 + blk * NS + r] = m;
        }
        __syncthreads();
        ull win = win_sh;
#pragma unroll
        for (int q = 0; q < 4; ++q) { if (kk[q] == win) kk[q] = 0ull; }
    }
}

// ---------------- K2b: top-12 stage 2 (merge 384 candidates per side) ----------------
__global__ __launch_bounds__(384) void k_topk2(const ull* __restrict__ cand,
                                               int* __restrict__ sel) {
    const int side = blockIdx.x;
    const int tid = threadIdx.x;
    const int wave = tid >> 6, lane = tid & 63;

    ull key = cand[side * 384 + tid];

    __shared__ ull wbest[6];
    __shared__ ull win_sh;

    for (int r = 0; r < NS; ++r) {
        ull b = key;
#pragma unroll
        for (int m2 = 1; m2 < 64; m2 <<= 1) {
            ull o = __shfl_xor(b, m2, 64);
            b = (o > b) ? o : b;
        }
        if (lane == 0) wbest[wave] = b;
        __syncthreads();
        if (tid == 0) {
            ull m = wbest[0];
#pragma unroll
            for (int ww = 1; ww < 6; ++ww) m = (wbest[ww] > m) ? wbest[ww] : m;
            win_sh = m;
            sel[side * NS + r] = (int)(0xFFFFFFFFu - (unsigned)(m & 0xFFFFFFFFull));
        }
        __syncthreads();
        if (key == win_sh) key = 0ull;
    }
}

// ---------------- K3: gather selected pixels + normalize ----------------
__global__ __launch_bounds__(256) void k_gather(const float* __restrict__ F,
                                                const int* __restrict__ sel,
                                                float* __restrict__ feats) {
    int b = blockIdx.x;                  // 0..23
    int s = sel[b];
    int n = s >> 12, hw = s & 4095;
    const float* fp = F + ((size_t)n * CC) * HW + hw;
    int tid = threadIdx.x;

    float v0 = fp[(size_t)(tid)       * HW];
    float v1 = fp[(size_t)(tid + 256) * HW];
    float v2 = fp[(size_t)(tid + 512) * HW];
    __shared__ float red[256];
    red[tid] = v0 * v0 + v1 * v1 + v2 * v2;
    __syncthreads();
    for (int off = 128; off > 0; off >>= 1) { if (tid < off) red[tid] += red[tid + off]; __syncthreads(); }
    float inv = 1.f / fmaxf(sqrtf(red[0]), 1e-8f);
    feats[b * CC + tid]       = v0 * inv;
    feats[b * CC + tid + 256] = v1 * inv;
    feats[b * CC + tid + 512] = v2 * inv;
}

// ---------------- K4: refinement, one wave per prototype ----------------
__global__ __launch_bounds__(640) void k_refine(const float* __restrict__ feats_all,
                                                const float* __restrict__ fg,
                                                const float* __restrict__ bg,
                                                float* __restrict__ pfg,
                                                float* __restrict__ pbg) {
    __shared__ float fe[NS * CC];
    __shared__ float dots[NS][KP];
    __shared__ int   assign[NS];

    const int tid  = threadIdx.x;
    const int k    = __builtin_amdgcn_readfirstlane(tid >> 6);   // wave id = proto id
    const int lane = tid & 63;
    const float* feats = feats_all + blockIdx.x * (NS * CC);
    const float* p0    = (blockIdx.x == 0) ? fg : bg;
    float* pout        = (blockIdx.x == 0) ? pfg : pbg;

    for (int i = tid; i < NS * CC; i += 640) fe[i] = feats[i];
    float p[12];
#pragma unroll
    for (int j = 0; j < 12; ++j) p[j] = p0[k * CC + j * 64 + lane];
    __syncthreads();

    for (int it = 0; it < 10; ++it) {
        float step = 0.1f / (1.0f + 0.5f * (float)it);

        float d[NS];
#pragma unroll
        for (int s = 0; s < NS; ++s) d[s] = 0.f;
#pragma unroll
        for (int j = 0; j < 12; ++j) {
            float pvj = p[j];
#pragma unroll
            for (int s = 0; s < NS; ++s) d[s] = fmaf(fe[s * CC + j * 64 + lane], pvj, d[s]);
        }
#pragma unroll
        for (int s = 0; s < NS; ++s) {
#pragma unroll
            for (int m2 = 1; m2 < 64; m2 <<= 1) d[s] += __shfl_xor(d[s], m2, 64);
        }
        if (lane == 0) {
#pragma unroll
            for (int s = 0; s < NS; ++s) dots[s][k] = d[s];
        }
        __syncthreads();

        if (tid < NS) {
            float bv = dots[tid][0]; int bk = 0;
#pragma unroll
            for (int kk = 1; kk < KP; ++kk) { float v = dots[tid][kk]; if (v > bv) { bv = v; bk = kk; } }
            assign[tid] = bk;
        }
        __syncthreads();

        int a[NS]; int cnt = 0;
#pragma unroll
        for (int s = 0; s < NS; ++s) { a[s] = assign[s]; cnt += (a[s] == k) ? 1 : 0; }

        if (cnt > 0) {
            float mac[12];
#pragma unroll
            for (int j = 0; j < 12; ++j) mac[j] = 0.f;
#pragma unroll
            for (int s = 0; s < NS; ++s) {
                if (a[s] == k) {   // wave-uniform branch
#pragma unroll
                    for (int j = 0; j < 12; ++j) mac[j] += fe[s * CC + j * 64 + lane];
                }
            }
            float fcnt = (float)cnt;
            float v[12]; float ss = 0.f;
#pragma unroll
            for (int j = 0; j < 12; ++j) {
                float mean = mac[j] / fcnt;
                v[j] = (1.0f - step) * p[j] + step * mean;
                ss = fmaf(v[j], v[j], ss);
            }
#pragma unroll
            for (int m2 = 1; m2 < 64; m2 <<= 1) ss += __shfl_xor(ss, m2, 64);
            float inv = 1.f / fmaxf(sqrtf(ss), 1e-8f);
#pragma unroll
            for (int j = 0; j < 12; ++j) p[j] = v[j] * inv;
        }
    }

#pragma unroll
    for (int j = 0; j < 12; ++j) pout[k * CC + j * 64 + lane] = p[j];
}

// ---------------- K5: triplet + InfoNCE loss ----------------
__global__ __launch_bounds__(256) void k_loss(const float* __restrict__ feats,
                                              const float* __restrict__ pfg,
                                              const float* __restrict__ pbg,
                                              float* __restrict__ out) {
    __shared__ float dots3[NS * 30];   // [s][g*10+k]: g=0 pos@pfg, g=1 neg@pfg, g=2 pos@pbg
    __shared__ float mp[NS], mn[NS], infon[NS];
    int tid = threadIdx.x, wave = tid >> 6, lane = tid & 63;

    for (int pid = wave; pid < 360; pid += 4) {
        int g = pid / 120, r = pid % 120, s = r / KP, k = r % KP;
        const float4* a4 = (const float4*)(feats + ((g == 1 ? NS + s : s) * CC) + lane * 12);
        const float4* b4 = (const float4*)((g == 2 ? pbg : pfg) + k * CC + lane * 12);
        float acc = 0.f;
#pragma unroll
        for (int j = 0; j < 3; ++j) {
            float4 a = a4[j], b = b4[j];
            acc += a.x * b.x + a.y * b.y + a.z * b.z + a.w * b.w;
        }
#pragma unroll
        for (int m2 = 1; m2 < 64; m2 <<= 1) acc += __shfl_xor(acc, m2, 64);
        if (lane == 0) dots3[s * 30 + g * 10 + k] = acc;
    }
    __syncthreads();

    if (tid < NS) {
        const float* d = &dots3[tid * 30];
        float maxp = d[0], maxn = d[10];
#pragma unroll
        for (int k = 1; k < KP; ++k) { maxp = fmaxf(maxp, d[k]); maxn = fmaxf(maxn, d[10 + k]); }
        mp[tid] = maxp; mn[tid] = maxn;

        float x[KP], y[KP];
#pragma unroll
        for (int k = 0; k < KP; ++k) { x[k] = d[k] / 0.07f; y[k] = d[20 + k] / 0.07f; }
        float m10 = x[0];
#pragma unroll
        for (int k = 1; k < KP; ++k) m10 = fmaxf(m10, x[k]);
        float se = 0.f;
#pragma unroll
        for (int k = 0; k < KP; ++k) se += expf(x[k] - m10);
        float numer = logf(se) + m10;
        float m20 = m10;
#pragma unroll
        for (int k = 0; k < KP; ++k) m20 = fmaxf(m20, y[k]);
        float se2 = 0.f;
#pragma unroll
        for (int k = 0; k < KP; ++k) se2 += expf(x[k] - m20);
#pragma unroll
        for (int k = 0; k < KP; ++k) se2 += expf(y[k] - m20);
        float denom = logf(se2) + m20;
        infon[tid] = numer - denom;
    }
    __syncthreads();
    if (tid == 0) {
        float sp = 0.f, sn = 0.f, si = 0.f;
        for (int s = 0; s < NS; ++s) { sp += mp[s]; sn += mn[s]; si += infon[s]; }
        sp /= 12.f; sn /= 12.f; si /= 12.f;
        float loss = fmaxf(0.2f + sn - sp, 0.f) + 0.25f * (-si);
        out[0] = loss;
    }
}

// ---------------- K6: blend + renormalize refined prototypes ----------------
__global__ __launch_bounds__(256) void k_blend(const float* __restrict__ fg,
                                               const float* __restrict__ bg,
                                               const float* __restrict__ pfg,
                                               const float* __restrict__ pbg,
                                               float* __restrict__ out) {
    __shared__ float red[256];
    int r = blockIdx.x, tid = threadIdx.x;
    const float* a = (r < 10) ? (fg + r * CC) : (bg + (r - 10) * CC);
    const float* b = (r < 10) ? (pfg + r * CC) : (pbg + (r - 10) * CC);
    float v[3]; float ss = 0.f;
#pragma unroll
    for (int cc = 0; cc < 3; ++cc) {
        int c = tid + cc * 256;
        v[cc] = (1.0f - 0.3f) * a[c] + 0.3f * b[c];
        ss += v[cc] * v[cc];
    }
    red[tid] = ss; __syncthreads();
    for (int off = 128; off > 0; off >>= 1) { if (tid < off) red[tid] += red[tid + off]; __syncthreads(); }
    float inv = 1.f / fmaxf(sqrtf(red[0]), 1e-8f);
    float* o = out + 1 + r * CC;   // fg rows 0..9, bg rows 10..19 are contiguous in out
#pragma unroll
    for (int cc = 0; cc < 3; ++cc) o[tid + cc * 256] = v[cc] * inv;
}

extern "C" void kernel_launch(void* const* d_in, const int* in_sizes, int n_in,
                              void* d_out, int out_size, void* d_ws, size_t ws_size,
                              hipStream_t stream) {
    const float* fg = (const float*)d_in[0];   // [10,768]
    const float* bg = (const float*)d_in[1];   // [10,768]
    const float* F  = (const float*)d_in[2];   // [8,768,64,64]
    const float* M  = (const float*)d_in[3];   // [8,1,64,64]
    float* out = (float*)d_out;                // [1 + 7680 + 7680]

    float* w    = (float*)d_ws;
    float* sfg  = w + WS_SCORE_FG;
    float* sbg  = w + WS_SCORE_BG;
    int*   sel  = (int*)(w + WS_SEL);
    float* fea  = w + WS_FEATS;
    float* pfg  = w + WS_PFG;
    float* pbg  = w + WS_PBG;
    ull*   cand = (ull*)(w + WS_CAND);   // overlaps pfg; consumed before refine writes

    k_scores<<<512, 512, 0, stream>>>(fg, bg, F, M, sfg, sbg);
    k_topk1 <<<64, 256, 0, stream>>>(w, cand);
    k_topk2 <<<2, 384, 0, stream>>>(cand, sel);
    k_gather<<<24, 256, 0, stream>>>(F, sel, fea);
    k_refine<<<2, 640, 0, stream>>>(fea, fg, bg, pfg, pbg);
    k_loss  <<<1, 256, 0, stream>>>(fea, pfg, pbg, out);
    k_blend <<<20, 256, 0, stream>>>(fg, bg, pfg, pbg, out);
}